// Round 4
// baseline (145.223 us; speedup 1.0000x reference)
//
#include <hip/hip_runtime.h>
#include <hip/hip_bf16.h>

typedef __attribute__((ext_vector_type(8))) short short8;
typedef __attribute__((ext_vector_type(4))) float f32x4;

#define B_SZ 64
#define T_SZ 8192
#define D_SZ 128
#define U_SZ 128
#define T_TILE 128
#define N_TILES (T_SZ / T_TILE)   /* 64 tiles per batch */
#define P_STRIDE 132              /* c[128] + m + s, padded */
#define WT_LD 136                 /* bf16 row stride: 272B -> breaks pow2 bank alias */

__device__ __forceinline__ unsigned short f2bf(float f) {
  // round-to-nearest-even fp32 -> bf16
  unsigned int u = __builtin_bit_cast(unsigned int, f);
  u += 0x7fffu + ((u >> 16) & 1u);
  return (unsigned short)(u >> 16);
}

__device__ __forceinline__ float bf2f(unsigned short s) {
  return __builtin_bit_cast(float, (unsigned int)s << 16);
}

__device__ __forceinline__ float fast_tanh(float x) {
  // tanh(x) = 1 - 2/(e^{2x}+1); saturates correctly at +-inf
  float e = __expf(2.0f * x);
  return 1.0f - 2.0f * __builtin_amdgcn_rcpf(e + 1.0f);
}

// DPP row-reduce within each 16-lane row: VALU pipe only, no LDS/permute.
// After shr 8,4,2,1 the row sum lands in lane (lr==15) of each 16-lane row.
template<int CTRL>
__device__ __forceinline__ float dpp_add(float v) {
  int t = __builtin_amdgcn_update_dpp(0, __builtin_bit_cast(int, v),
                                      CTRL, 0xf, 0xf, true);
  return v + __builtin_bit_cast(float, t);
}
__device__ __forceinline__ float row_reduce16(float v) {
  v = dpp_add<0x118>(v);  // row_shr:8
  v = dpp_add<0x114>(v);  // row_shr:4
  v = dpp_add<0x112>(v);  // row_shr:2
  v = dpp_add<0x111>(v);  // row_shr:1
  return v;               // lane 15 (within each row of 16) holds the sum
}

// ---------------------------------------------------------------------------
// Kernel 0: W [d][u] fp32 -> Wt [u][d] bf16 in workspace (once, tiny)
// ---------------------------------------------------------------------------
__global__ void k_prep(const float* __restrict__ wk, unsigned short* __restrict__ wt) {
  int i = blockIdx.x * 256 + threadIdx.x;     // 16384 elements
  if (i < D_SZ * U_SZ) {
    int d = i >> 7, u = i & 127;
    wt[u * D_SZ + d] = f2bf(wk[i]);
  }
}

// ---------------------------------------------------------------------------
// Kernel 1: per (b, T-tile of 128). Single x read (afrag registers serve both
// MFMA logits and the weighted context). Wt in padded LDS (R0 structure).
// All 16-lane reductions via DPP adds (VALU) — no shfl/LDS-pipe storm (R2's
// regression) and no second global x read (R0's 2x HBM).
// ---------------------------------------------------------------------------
__global__ __launch_bounds__(256, 4) void k_partial(
    const float* __restrict__ x, const unsigned short* __restrict__ wt_g,
    const float* __restrict__ wb, const float* __restrict__ v,
    const float* __restrict__ vb, float* __restrict__ pbuf)
{
  __shared__ unsigned short wt[U_SZ][WT_LD];  // 34816 B
  __shared__ float wb_s[U_SZ], v_s[U_SZ];
  __shared__ float logits[T_TILE];
  __shared__ float pw[T_TILE];
  __shared__ float msum[2];
  __shared__ float cpar[4][D_SZ];             // per-wave context partials

  const int tid  = threadIdx.x;
  const int bidx = blockIdx.x;
  const int b    = bidx >> 6;       // /N_TILES
  const int tile = bidx & 63;

  // stage Wt (bf16, already [u][d]) into padded LDS; 16B chunks, coalesced
  for (int i = tid; i < U_SZ * 16; i += 256) {
    int row = i >> 4, c16 = i & 15;
    uint4 val = ((const uint4*)wt_g)[i];
    *(uint4*)&wt[row][c16 * 8] = val;
  }
  if (tid < U_SZ) { wb_s[tid] = wb[tid]; v_s[tid] = v[tid]; }
  __syncthreads();

  const int w  = tid >> 6;          // wave 0..3, owns rows w*32..w*32+31
  const int l  = tid & 63;
  const int lr = l & 15;            // A-row / B-col / D-col lane index
  const int lh = l >> 4;            // 0..3 -> k-subchunk / D-row group
  const size_t xbase = ((size_t)b * T_SZ + (size_t)tile * T_TILE) * D_SZ;

  // A fragments: 2 row-subtiles x 4 k-tiles, from global fp32 (single read)
  short8 afrag[2][4];
#pragma unroll
  for (int s = 0; s < 2; ++s) {
    const float* xr = x + xbase + (size_t)(w * 32 + s * 16 + lr) * D_SZ;
#pragma unroll
    for (int kt = 0; kt < 4; ++kt) {
      const float4 f0 = *(const float4*)(xr + kt * 32 + lh * 8);
      const float4 f1 = *(const float4*)(xr + kt * 32 + lh * 8 + 4);
      short8 a;
      a[0] = (short)f2bf(f0.x); a[1] = (short)f2bf(f0.y);
      a[2] = (short)f2bf(f0.z); a[3] = (short)f2bf(f0.w);
      a[4] = (short)f2bf(f1.x); a[5] = (short)f2bf(f1.y);
      a[6] = (short)f2bf(f1.z); a[7] = (short)f2bf(f1.w);
      afrag[s][kt] = a;
    }
  }

  // logit accumulators per lane (partial row-sums over this lane's u-column)
  float lg0[4] = {0.f, 0.f, 0.f, 0.f};
  float lg1[4] = {0.f, 0.f, 0.f, 0.f};

#pragma unroll
  for (int ut = 0; ut < 8; ++ut) {
    f32x4 acc0 = {0.f, 0.f, 0.f, 0.f};
    f32x4 acc1 = {0.f, 0.f, 0.f, 0.f};
#pragma unroll
    for (int kt = 0; kt < 4; ++kt) {
      short8 bfrag = *(const short8*)&wt[ut * 16 + lr][kt * 32 + lh * 8];
      acc0 = __builtin_amdgcn_mfma_f32_16x16x32_bf16(afrag[0][kt], bfrag, acc0, 0, 0, 0);
      acc1 = __builtin_amdgcn_mfma_f32_16x16x32_bf16(afrag[1][kt], bfrag, acc1, 0, 0, 0);
    }
    const float wbv = wb_s[ut * 16 + lr];
    const float vv  = v_s[ut * 16 + lr];
#pragma unroll
    for (int r = 0; r < 4; ++r) {
      lg0[r] += fast_tanh(acc0[r] + wbv) * vv;
      lg1[r] += fast_tanh(acc1[r] + wbv) * vv;
    }
  }

  // reduce over the 16 u-columns via DPP (result in lane lr==15 of each row)
#pragma unroll
  for (int r = 0; r < 4; ++r) {
    lg0[r] = row_reduce16(lg0[r]);
    lg1[r] = row_reduce16(lg1[r]);
  }
  const float vbias = vb[0];
  if (lr == 15) {
#pragma unroll
    for (int r = 0; r < 4; ++r) {
      logits[w * 32 +      lh * 4 + r] = lg0[r] + vbias;
      logits[w * 32 + 16 + lh * 4 + r] = lg1[r] + vbias;
    }
  }
  __syncthreads();

  // tile softmax partials (wave 0)
  if (tid < 64) {
    float l0 = logits[tid], l1 = logits[64 + tid];
    float mx = fmaxf(l0, l1);
#pragma unroll
    for (int m = 1; m <= 32; m <<= 1) mx = fmaxf(mx, __shfl_xor(mx, m, 64));
    float p0 = __expf(l0 - mx), p1 = __expf(l1 - mx);
    float ss = p0 + p1;
#pragma unroll
    for (int m = 1; m <= 32; m <<= 1) ss += __shfl_xor(ss, m, 64);
    pw[tid] = p0; pw[64 + tid] = p1;
    if (tid == 0) { msum[0] = mx; msum[1] = ss; }
  }
  __syncthreads();

  // ---- weighted context straight from afrag registers ----
  // this thread holds rows t0 = w*32+lr, t1 = w*32+16+lr,
  // columns { kt*32 + lh*8 + j }. Reduce over lr via DPP rows.
  const float p0 = pw[w * 32 + lr];          // 16 addrs x 4-lane broadcast: free
  const float p1 = pw[w * 32 + 16 + lr];
  float csum[4][8];
#pragma unroll
  for (int kt = 0; kt < 4; ++kt) {
#pragma unroll
    for (int j = 0; j < 8; ++j) {
      float cv = fmaf(p1, bf2f((unsigned short)afrag[1][kt][j]),
                      p0 * bf2f((unsigned short)afrag[0][kt][j]));
      csum[kt][j] = row_reduce16(cv);
    }
  }
  if (lr == 15) {   // 4 lanes per wave (lh=0..3), banks 0/8/16/24: conflict-free
#pragma unroll
    for (int kt = 0; kt < 4; ++kt) {
      f32x4 v0 = {csum[kt][0], csum[kt][1], csum[kt][2], csum[kt][3]};
      f32x4 v1 = {csum[kt][4], csum[kt][5], csum[kt][6], csum[kt][7]};
      *(f32x4*)&cpar[w][kt * 32 + lh * 8]     = v0;
      *(f32x4*)&cpar[w][kt * 32 + lh * 8 + 4] = v1;
    }
  }
  __syncthreads();

  float* pb = pbuf + (size_t)bidx * P_STRIDE;
  if (tid < 128) {
    pb[tid] = cpar[0][tid] + cpar[1][tid] + cpar[2][tid] + cpar[3][tid];
  } else if (tid == 128) pb[128] = msum[0];
  else if (tid == 129) pb[129] = msum[1];
}

// ---------------------------------------------------------------------------
// Kernel 2: combine 64 tile-partials per batch with global softmax rescale
// ---------------------------------------------------------------------------
__global__ __launch_bounds__(128) void k_combine(const float* __restrict__ pbuf,
                                                 float* __restrict__ out)
{
  const int b = blockIdx.x, tid = threadIdx.x;
  __shared__ float sc[N_TILES];
  __shared__ float stot_s;
  const float* pb = pbuf + (size_t)b * N_TILES * P_STRIDE;

  if (tid < 64) {
    float m = pb[tid * P_STRIDE + 128];
    float mx = m;
#pragma unroll
    for (int k = 1; k <= 32; k <<= 1) mx = fmaxf(mx, __shfl_xor(mx, k, 64));
    float e = __expf(m - mx);
    float s = pb[tid * P_STRIDE + 129] * e;
    float st = s;
#pragma unroll
    for (int k = 1; k <= 32; k <<= 1) st += __shfl_xor(st, k, 64);
    sc[tid] = e;
    if (tid == 0) stot_s = st;
  }
  __syncthreads();

  float c = 0.0f;
#pragma unroll 8
  for (int i = 0; i < N_TILES; ++i) c = fmaf(pb[(size_t)i * P_STRIDE + tid], sc[i], c);
  out[b * D_SZ + tid] = c / stot_s;
}

// ---------------------------------------------------------------------------
extern "C" void kernel_launch(void* const* d_in, const int* in_sizes, int n_in,
                              void* d_out, int out_size, void* d_ws, size_t ws_size,
                              hipStream_t stream) {
  const float* x  = (const float*)d_in[0];  // [B,T,D]
  const float* wk = (const float*)d_in[1];  // [D,U]
  const float* wb = (const float*)d_in[2];  // [U]
  const float* vk = (const float*)d_in[3];  // [U,1]
  const float* vb = (const float*)d_in[4];  // [1]
  float* out = (float*)d_out;               // [B,D]

  unsigned short* wt = (unsigned short*)d_ws;               // 32 KB bf16 Wt[u][d]
  float* pbuf = (float*)((char*)d_ws + 32768);              // 4096 * 132 floats

  k_prep<<<64, 256, 0, stream>>>(wk, wt);
  k_partial<<<B_SZ * N_TILES, 256, 0, stream>>>(x, wt, wb, vk, vb, pbuf);
  k_combine<<<B_SZ, 128, 0, stream>>>(pbuf, out);
}

// Round 5
// 79.095 us; speedup vs baseline: 1.8361x; 1.8361x over previous
//
#include <hip/hip_runtime.h>
#include <hip/hip_bf16.h>

typedef __attribute__((ext_vector_type(8))) short short8;
typedef __attribute__((ext_vector_type(4))) float f32x4;

#define B_SZ 64
#define T_SZ 8192
#define D_SZ 128
#define U_SZ 128
#define T_TILE 128
#define N_TILES (T_SZ / T_TILE)   /* 64 tiles per batch */
#define P_STRIDE 132              /* c[128] + m + s, padded */
#define WT_LD 136                 /* bf16 row stride: 272B */

__device__ __forceinline__ unsigned short f2bf(float f) {
  // round-to-nearest-even fp32 -> bf16
  unsigned int u = __builtin_bit_cast(unsigned int, f);
  u += 0x7fffu + ((u >> 16) & 1u);
  return (unsigned short)(u >> 16);
}

__device__ __forceinline__ float bf2f(unsigned short s) {
  return __builtin_bit_cast(float, (unsigned int)s << 16);
}

__device__ __forceinline__ float fast_tanh(float x) {
  // tanh(x) = 1 - 2/(e^{2x}+1); saturates correctly at +-inf
  float e = __expf(2.0f * x);
  return 1.0f - 2.0f * __builtin_amdgcn_rcpf(e + 1.0f);
}

// DPP row-reduce within each 16-lane row: VALU pipe only, no LDS/permute.
template<int CTRL>
__device__ __forceinline__ float dpp_add(float v) {
  int t = __builtin_amdgcn_update_dpp(0, __builtin_bit_cast(int, v),
                                      CTRL, 0xf, 0xf, true);
  return v + __builtin_bit_cast(float, t);
}
__device__ __forceinline__ float row_reduce16(float v) {
  v = dpp_add<0x118>(v);  // row_shr:8
  v = dpp_add<0x114>(v);  // row_shr:4
  v = dpp_add<0x112>(v);  // row_shr:2
  v = dpp_add<0x111>(v);  // row_shr:1
  return v;               // lane 15 (within each row of 16) holds the sum
}

// ---------------------------------------------------------------------------
// Kernel 0: W [d][u] fp32 -> Wt [u][d] bf16 in workspace (once, tiny)
// ---------------------------------------------------------------------------
__global__ void k_prep(const float* __restrict__ wk, unsigned short* __restrict__ wt) {
  int i = blockIdx.x * 256 + threadIdx.x;     // 16384 elements
  if (i < D_SZ * U_SZ) {
    int d = i >> 7, u = i & 127;
    wt[u * D_SZ + d] = f2bf(wk[i]);
  }
}

// ---------------------------------------------------------------------------
// Kernel 1: per (b, T-tile of 128). Single x read (afrag registers serve both
// MFMA logits and the weighted context). Wt in padded LDS.
// NOTE: no min-waves launch_bounds arg — R2/R3's (256,4) capped the allocator
// at 64 VGPRs and spilled ~150 B/thread to scratch (157 MB WRITE_SIZE).
// Context phase reduces per-kt to keep peak live regs ~70.
// ---------------------------------------------------------------------------
__global__ __launch_bounds__(256) void k_partial(
    const float* __restrict__ x, const unsigned short* __restrict__ wt_g,
    const float* __restrict__ wb, const float* __restrict__ v,
    const float* __restrict__ vb, float* __restrict__ pbuf)
{
  __shared__ unsigned short wt[U_SZ][WT_LD];  // 34816 B
  __shared__ float wb_s[U_SZ], v_s[U_SZ];
  __shared__ float logits[T_TILE];
  __shared__ float pw[T_TILE];
  __shared__ float msum[2];
  __shared__ float cpar[4][D_SZ];             // per-wave context partials

  const int tid  = threadIdx.x;
  const int bidx = blockIdx.x;
  const int b    = bidx >> 6;       // /N_TILES
  const int tile = bidx & 63;

  // stage Wt (bf16, already [u][d]) into padded LDS; 16B chunks, coalesced
  for (int i = tid; i < U_SZ * 16; i += 256) {
    int row = i >> 4, c16 = i & 15;
    uint4 val = ((const uint4*)wt_g)[i];
    *(uint4*)&wt[row][c16 * 8] = val;
  }
  if (tid < U_SZ) { wb_s[tid] = wb[tid]; v_s[tid] = v[tid]; }
  __syncthreads();

  const int w  = tid >> 6;          // wave 0..3, owns rows w*32..w*32+31
  const int l  = tid & 63;
  const int lr = l & 15;            // A-row / B-col / D-col lane index
  const int lh = l >> 4;            // 0..3 -> k-subchunk / D-row group
  const size_t xbase = ((size_t)b * T_SZ + (size_t)tile * T_TILE) * D_SZ;

  // A fragments: 2 row-subtiles x 4 k-tiles, from global fp32 (single read)
  short8 afrag[2][4];
#pragma unroll
  for (int s = 0; s < 2; ++s) {
    const float* xr = x + xbase + (size_t)(w * 32 + s * 16 + lr) * D_SZ;
#pragma unroll
    for (int kt = 0; kt < 4; ++kt) {
      const float4 f0 = *(const float4*)(xr + kt * 32 + lh * 8);
      const float4 f1 = *(const float4*)(xr + kt * 32 + lh * 8 + 4);
      short8 a;
      a[0] = (short)f2bf(f0.x); a[1] = (short)f2bf(f0.y);
      a[2] = (short)f2bf(f0.z); a[3] = (short)f2bf(f0.w);
      a[4] = (short)f2bf(f1.x); a[5] = (short)f2bf(f1.y);
      a[6] = (short)f2bf(f1.z); a[7] = (short)f2bf(f1.w);
      afrag[s][kt] = a;
    }
  }

  // logit accumulators per lane (partial row-sums over this lane's u-column)
  float lg0[4] = {0.f, 0.f, 0.f, 0.f};
  float lg1[4] = {0.f, 0.f, 0.f, 0.f};

#pragma unroll
  for (int ut = 0; ut < 8; ++ut) {
    f32x4 acc0 = {0.f, 0.f, 0.f, 0.f};
    f32x4 acc1 = {0.f, 0.f, 0.f, 0.f};
#pragma unroll
    for (int kt = 0; kt < 4; ++kt) {
      short8 bfrag = *(const short8*)&wt[ut * 16 + lr][kt * 32 + lh * 8];
      acc0 = __builtin_amdgcn_mfma_f32_16x16x32_bf16(afrag[0][kt], bfrag, acc0, 0, 0, 0);
      acc1 = __builtin_amdgcn_mfma_f32_16x16x32_bf16(afrag[1][kt], bfrag, acc1, 0, 0, 0);
    }
    const float wbv = wb_s[ut * 16 + lr];
    const float vv  = v_s[ut * 16 + lr];
#pragma unroll
    for (int r = 0; r < 4; ++r) {
      lg0[r] += fast_tanh(acc0[r] + wbv) * vv;
      lg1[r] += fast_tanh(acc1[r] + wbv) * vv;
    }
  }

  // reduce over the 16 u-columns via DPP (result in lane lr==15 of each row)
#pragma unroll
  for (int r = 0; r < 4; ++r) {
    lg0[r] = row_reduce16(lg0[r]);
    lg1[r] = row_reduce16(lg1[r]);
  }
  const float vbias = vb[0];
  if (lr == 15) {
#pragma unroll
    for (int r = 0; r < 4; ++r) {
      logits[w * 32 +      lh * 4 + r] = lg0[r] + vbias;
      logits[w * 32 + 16 + lh * 4 + r] = lg1[r] + vbias;
    }
  }
  __syncthreads();

  // tile softmax partials (wave 0)
  if (tid < 64) {
    float l0 = logits[tid], l1 = logits[64 + tid];
    float mx = fmaxf(l0, l1);
#pragma unroll
    for (int m = 1; m <= 32; m <<= 1) mx = fmaxf(mx, __shfl_xor(mx, m, 64));
    float p0 = __expf(l0 - mx), p1 = __expf(l1 - mx);
    float ss = p0 + p1;
#pragma unroll
    for (int m = 1; m <= 32; m <<= 1) ss += __shfl_xor(ss, m, 64);
    pw[tid] = p0; pw[64 + tid] = p1;
    if (tid == 0) { msum[0] = mx; msum[1] = ss; }
  }
  __syncthreads();

  // ---- weighted context straight from afrag registers ----
  // this thread holds rows t0 = w*32+lr, t1 = w*32+16+lr,
  // columns { kt*32 + lh*8 + j }. Reduce over lr via DPP, per kt to keep
  // only 8 partials live at a time.
  const float p0 = pw[w * 32 + lr];
  const float p1 = pw[w * 32 + 16 + lr];
#pragma unroll
  for (int kt = 0; kt < 4; ++kt) {
    float csum[8];
#pragma unroll
    for (int j = 0; j < 8; ++j) {
      float cv = fmaf(p1, bf2f((unsigned short)afrag[1][kt][j]),
                      p0 * bf2f((unsigned short)afrag[0][kt][j]));
      csum[j] = row_reduce16(cv);
    }
    if (lr == 15) {   // 4 lanes per wave (lh=0..3): conflict-free f32x4 stores
      f32x4 v0 = {csum[0], csum[1], csum[2], csum[3]};
      f32x4 v1 = {csum[4], csum[5], csum[6], csum[7]};
      *(f32x4*)&cpar[w][kt * 32 + lh * 8]     = v0;
      *(f32x4*)&cpar[w][kt * 32 + lh * 8 + 4] = v1;
    }
  }
  __syncthreads();

  float* pb = pbuf + (size_t)bidx * P_STRIDE;
  if (tid < 128) {
    pb[tid] = cpar[0][tid] + cpar[1][tid] + cpar[2][tid] + cpar[3][tid];
  } else if (tid == 128) pb[128] = msum[0];
  else if (tid == 129) pb[129] = msum[1];
}

// ---------------------------------------------------------------------------
// Kernel 2: combine 64 tile-partials per batch with global softmax rescale
// ---------------------------------------------------------------------------
__global__ __launch_bounds__(128) void k_combine(const float* __restrict__ pbuf,
                                                 float* __restrict__ out)
{
  const int b = blockIdx.x, tid = threadIdx.x;
  __shared__ float sc[N_TILES];
  __shared__ float stot_s;
  const float* pb = pbuf + (size_t)b * N_TILES * P_STRIDE;

  if (tid < 64) {
    float m = pb[tid * P_STRIDE + 128];
    float mx = m;
#pragma unroll
    for (int k = 1; k <= 32; k <<= 1) mx = fmaxf(mx, __shfl_xor(mx, k, 64));
    float e = __expf(m - mx);
    float s = pb[tid * P_STRIDE + 129] * e;
    float st = s;
#pragma unroll
    for (int k = 1; k <= 32; k <<= 1) st += __shfl_xor(st, k, 64);
    sc[tid] = e;
    if (tid == 0) stot_s = st;
  }
  __syncthreads();

  float c = 0.0f;
#pragma unroll 8
  for (int i = 0; i < N_TILES; ++i) c = fmaf(pb[(size_t)i * P_STRIDE + tid], sc[i], c);
  out[b * D_SZ + tid] = c / stot_s;
}

// ---------------------------------------------------------------------------
extern "C" void kernel_launch(void* const* d_in, const int* in_sizes, int n_in,
                              void* d_out, int out_size, void* d_ws, size_t ws_size,
                              hipStream_t stream) {
  const float* x  = (const float*)d_in[0];  // [B,T,D]
  const float* wk = (const float*)d_in[1];  // [D,U]
  const float* wb = (const float*)d_in[2];  // [U]
  const float* vk = (const float*)d_in[3];  // [U,1]
  const float* vb = (const float*)d_in[4];  // [1]
  float* out = (float*)d_out;               // [B,D]

  unsigned short* wt = (unsigned short*)d_ws;               // 32 KB bf16 Wt[u][d]
  float* pbuf = (float*)((char*)d_ws + 32768);              // 4096 * 132 floats

  k_prep<<<64, 256, 0, stream>>>(wk, wt);
  k_partial<<<B_SZ * N_TILES, 256, 0, stream>>>(x, wt, wb, vk, vb, pbuf);
  k_combine<<<B_SZ, 128, 0, stream>>>(pbuf, out);
}

// Round 6
// 71.627 us; speedup vs baseline: 2.0275x; 1.1043x over previous
//
#include <hip/hip_runtime.h>
#include <hip/hip_bf16.h>

typedef __attribute__((ext_vector_type(8))) short short8;
typedef __attribute__((ext_vector_type(4))) float f32x4;

#define B_SZ 64
#define T_SZ 8192
#define D_SZ 128
#define U_SZ 128
#define T_TILE 64
#define GRID_P 1024
#define TILES_PER_BLK 8           /* 1024 blocks x 8 tiles x 64 rows = 64*8192 */
#define P_STRIDE 132              /* c[128] + m + s, padded */
#define WT_LD 136                 /* bf16 row stride: 272B */

__device__ __forceinline__ unsigned short f2bf(float f) {
  unsigned int u = __builtin_bit_cast(unsigned int, f);
  u += 0x7fffu + ((u >> 16) & 1u);
  return (unsigned short)(u >> 16);
}

__device__ __forceinline__ float bf2f(unsigned short s) {
  return __builtin_bit_cast(float, (unsigned int)s << 16);
}

__device__ __forceinline__ float fast_tanh(float x) {
  float e = __expf(2.0f * x);
  return 1.0f - 2.0f * __builtin_amdgcn_rcpf(e + 1.0f);
}

// DPP row-reduce within each 16-lane row (VALU pipe only).
template<int CTRL>
__device__ __forceinline__ float dpp_add(float v) {
  int t = __builtin_amdgcn_update_dpp(0, __builtin_bit_cast(int, v),
                                      CTRL, 0xf, 0xf, true);
  return v + __builtin_bit_cast(float, t);
}
__device__ __forceinline__ float row_reduce16(float v) {
  v = dpp_add<0x118>(v);  // row_shr:8
  v = dpp_add<0x114>(v);  // row_shr:4
  v = dpp_add<0x112>(v);  // row_shr:2
  v = dpp_add<0x111>(v);  // row_shr:1
  return v;               // lane lr==15 of each 16-lane row holds the sum
}

// ---------------------------------------------------------------------------
// Kernel 0: W [d][u] fp32 -> Wt [u][d] bf16 in workspace (once, tiny)
// ---------------------------------------------------------------------------
__global__ void k_prep(const float* __restrict__ wk, unsigned short* __restrict__ wt) {
  int i = blockIdx.x * 256 + threadIdx.x;
  if (i < D_SZ * U_SZ) {
    int d = i >> 7, u = i & 127;
    wt[u * D_SZ + d] = f2bf(wk[i]);
  }
}

// ---------------------------------------------------------------------------
// Kernel 1: 1024 persistent-ish blocks, each sweeps 8 contiguous 64-row tiles
// of one batch. Register prefetch of tile i+1's fp32 x during tile i's
// compute keeps HBM loads in flight across the MFMA/softmax/context phases
// (R4 stalled at ~3 TB/s because compute phases had zero outstanding loads).
// Online-softmax (m,s,c) merged across the 8 tiles in LDS; one partial
// record per block.
// ---------------------------------------------------------------------------
__global__ __launch_bounds__(256) void k_partial(
    const float* __restrict__ x, const unsigned short* __restrict__ wt_g,
    const float* __restrict__ wb, const float* __restrict__ v,
    const float* __restrict__ vb, float* __restrict__ pbuf)
{
  __shared__ unsigned short wt[U_SZ][WT_LD];  // 34816 B
  __shared__ float wb_s[U_SZ], v_s[U_SZ];     // 1 KB
  __shared__ float logits[T_TILE];            // 256 B
  __shared__ float cpar[4][D_SZ];             // 2 KB
  __shared__ float cacc[D_SZ];                // 512 B running context

  const int tid  = threadIdx.x;
  const int bidx = blockIdx.x;

  // stage Wt into padded LDS; init running context
  for (int i = tid; i < U_SZ * 16; i += 256) {
    int row = i >> 4, c16 = i & 15;
    uint4 val = ((const uint4*)wt_g)[i];
    *(uint4*)&wt[row][c16 * 8] = val;
  }
  if (tid < U_SZ) { wb_s[tid] = wb[tid]; v_s[tid] = v[tid]; cacc[tid] = 0.0f; }
  __syncthreads();

  const int w  = tid >> 6;          // wave 0..3 -> rows w*16..w*16+15 of tile
  const int l  = tid & 63;
  const int lr = l & 15;            // A row within the wave's 16-row subtile
  const int lh = l >> 4;            // k-subchunk / D-row group
  const float vbias = vb[0];

  // block's batch and starting row: 16 blocks per batch, 512 rows each
  const int b        = bidx >> 4;
  const int row0     = (bidx & 15) * (TILES_PER_BLK * T_TILE);
  const float* xbase = x + ((size_t)b * T_SZ + row0 + w * 16 + lr) * D_SZ + lh * 8;

  float4 pf[8];
  // prologue: load tile 0
#pragma unroll
  for (int kt = 0; kt < 4; ++kt) {
    pf[kt * 2]     = *(const float4*)(xbase + kt * 32);
    pf[kt * 2 + 1] = *(const float4*)(xbase + kt * 32 + 4);
  }
  short8 afrag[4];
#pragma unroll
  for (int kt = 0; kt < 4; ++kt) {
    short8 a;
#pragma unroll
    for (int j = 0; j < 4; ++j) {
      float4 f = pf[kt * 2 + (j >> 1)];
      a[j * 2]     = (short)f2bf(j & 1 ? f.z : f.x);
      a[j * 2 + 1] = (short)f2bf(j & 1 ? f.w : f.y);
    }
    afrag[kt] = a;
  }

  float m_run = -3.0e38f, s_run = 0.0f;

  for (int it = 0; it < TILES_PER_BLK; ++it) {
    // issue prefetch for next tile (consumed after this tile's compute)
    if (it + 1 < TILES_PER_BLK) {
      const float* p = xbase + (size_t)(it + 1) * T_TILE * D_SZ;
#pragma unroll
      for (int kt = 0; kt < 4; ++kt) {
        pf[kt * 2]     = *(const float4*)(p + kt * 32);
        pf[kt * 2 + 1] = *(const float4*)(p + kt * 32 + 4);
      }
    }

    // ---- logits: 8 u-tiles x 4 k-tiles MFMA + tanh + v-weighted u-sum ----
    float lg[4] = {0.f, 0.f, 0.f, 0.f};
#pragma unroll
    for (int ut = 0; ut < 8; ++ut) {
      f32x4 acc = {0.f, 0.f, 0.f, 0.f};
#pragma unroll
      for (int kt = 0; kt < 4; ++kt) {
        short8 bfrag = *(const short8*)&wt[ut * 16 + lr][kt * 32 + lh * 8];
        acc = __builtin_amdgcn_mfma_f32_16x16x32_bf16(afrag[kt], bfrag, acc, 0, 0, 0);
      }
      const float wbv = wb_s[ut * 16 + lr];
      const float vv  = v_s[ut * 16 + lr];
#pragma unroll
      for (int r = 0; r < 4; ++r)
        lg[r] += fast_tanh(acc[r] + wbv) * vv;
    }
#pragma unroll
    for (int r = 0; r < 4; ++r) lg[r] = row_reduce16(lg[r]);
    if (lr == 15) {
#pragma unroll
      for (int r = 0; r < 4; ++r)
        logits[w * 16 + lh * 4 + r] = lg[r] + vbias;
    }
    __syncthreads();

    // ---- softmax over the 64 tile rows (redundant in every wave) ----
    float lv = logits[l];
    float mx = lv;
#pragma unroll
    for (int k = 1; k <= 32; k <<= 1) mx = fmaxf(mx, __shfl_xor(mx, k, 64));
    float ss = __expf(lv - mx);
#pragma unroll
    for (int k = 1; k <= 32; k <<= 1) ss += __shfl_xor(ss, k, 64);
    const float pr = __expf(logits[w * 16 + lr] - mx);  // own row's weight

    // ---- weighted context from afrag registers, reduce over 16 rows ----
#pragma unroll
    for (int kt = 0; kt < 4; ++kt) {
      float csum[8];
#pragma unroll
      for (int j = 0; j < 8; ++j)
        csum[j] = row_reduce16(pr * bf2f((unsigned short)afrag[kt][j]));
      if (lr == 15) {
        f32x4 v0 = {csum[0], csum[1], csum[2], csum[3]};
        f32x4 v1 = {csum[4], csum[5], csum[6], csum[7]};
        *(f32x4*)&cpar[w][kt * 32 + lh * 8]     = v0;
        *(f32x4*)&cpar[w][kt * 32 + lh * 8 + 4] = v1;
      }
    }
    __syncthreads();

    // ---- online merge into running (m,s,c) ----
    const float m_new = fmaxf(m_run, mx);
    const float e_old = __expf(m_run - m_new);
    const float e_t   = __expf(mx - m_new);
    if (tid < D_SZ) {
      float ct = cpar[0][tid] + cpar[1][tid] + cpar[2][tid] + cpar[3][tid];
      cacc[tid] = cacc[tid] * e_old + ct * e_t;
    }
    s_run = s_run * e_old + ss * e_t;
    m_run = m_new;

    // ---- convert prefetched fp32 -> afrag for next tile ----
    if (it + 1 < TILES_PER_BLK) {
#pragma unroll
      for (int kt = 0; kt < 4; ++kt) {
        short8 a;
#pragma unroll
        for (int j = 0; j < 4; ++j) {
          float4 f = pf[kt * 2 + (j >> 1)];
          a[j * 2]     = (short)f2bf(j & 1 ? f.z : f.x);
          a[j * 2 + 1] = (short)f2bf(j & 1 ? f.w : f.y);
        }
        afrag[kt] = a;
      }
    }
  }

  float* pb = pbuf + (size_t)bidx * P_STRIDE;
  if (tid < 128)       pb[tid] = cacc[tid];   // own element, no barrier needed
  else if (tid == 128) pb[128] = m_run;
  else if (tid == 129) pb[129] = s_run;
}

// ---------------------------------------------------------------------------
// Kernel 2: combine 16 block-partials per batch with global softmax rescale
// ---------------------------------------------------------------------------
__global__ __launch_bounds__(128) void k_combine(const float* __restrict__ pbuf,
                                                 float* __restrict__ out)
{
  const int b = blockIdx.x, tid = threadIdx.x;
  __shared__ float sm[16], sden[16];
  const float* base = pbuf + (size_t)b * 16 * P_STRIDE;

  if (tid < 16) {
    sm[tid]   = base[tid * P_STRIDE + 128];
    sden[tid] = base[tid * P_STRIDE + 129];
  }
  __syncthreads();

  float mx = -3.0e38f;
#pragma unroll
  for (int i = 0; i < 16; ++i) mx = fmaxf(mx, sm[i]);
  float den = 0.0f, c = 0.0f;
#pragma unroll
  for (int i = 0; i < 16; ++i) {
    float e = __expf(sm[i] - mx);
    den += sden[i] * e;
    c = fmaf(base[(size_t)i * P_STRIDE + tid], e, c);
  }
  out[b * D_SZ + tid] = c / den;
}

// ---------------------------------------------------------------------------
extern "C" void kernel_launch(void* const* d_in, const int* in_sizes, int n_in,
                              void* d_out, int out_size, void* d_ws, size_t ws_size,
                              hipStream_t stream) {
  const float* x  = (const float*)d_in[0];  // [B,T,D]
  const float* wk = (const float*)d_in[1];  // [D,U]
  const float* wb = (const float*)d_in[2];  // [U]
  const float* vk = (const float*)d_in[3];  // [U,1]
  const float* vb = (const float*)d_in[4];  // [1]
  float* out = (float*)d_out;               // [B,D]

  unsigned short* wt = (unsigned short*)d_ws;       // 32 KB bf16 Wt[u][d]
  float* pbuf = (float*)((char*)d_ws + 32768);      // 1024 * 132 floats (~540 KB)

  k_prep<<<64, 256, 0, stream>>>(wk, wt);
  k_partial<<<GRID_P, 256, 0, stream>>>(x, wt, wb, vk, vb, pbuf);
  k_combine<<<B_SZ, 128, 0, stream>>>(pbuf, out);
}